// Round 10
// baseline (226.248 us; speedup 1.0000x reference)
//
#include <hip/hip_runtime.h>
#include <hip/hip_bf16.h>
#include <cstdint>

typedef _Float16 f16;
typedef _Float16 f16x8 __attribute__((ext_vector_type(8)));
typedef _Float16 f16x4 __attribute__((ext_vector_type(4)));
typedef float    f32x4 __attribute__((ext_vector_type(4)));
typedef unsigned int u32;

#define DH 128

// Packed f16 weight layout (fragments for v_mfma_f32_16x16x32_f16):
//   packed[((ct*NKS + ks)*64 + lane)*8 + i] = W[rb + ks*32 + (lane>>4)*8 + i][ct*16 + (lane&15)]
#define PK_W0   0
#define PK_W1   16384
#define PK_W2   32768
#define PK_WG   49152
#define PK_R0A  65536
#define PK_R0B  81920
#define PK_R1   98304
#define PK_TOTAL 106496

__global__ void pack_weights_kernel(const float* __restrict__ W0, const float* __restrict__ W1,
                                    const float* __restrict__ W2, const float* __restrict__ Wg,
                                    const float* __restrict__ R0, const float* __restrict__ R1,
                                    f16* __restrict__ pk)
{
    int t = blockIdx.x * 256 + threadIdx.x;
    const float* W; int K, NC, local, rb = 0; f16* dst;
    if      (t < 2048)  { W = W0; K = 128; NC = 128; local = t;          dst = pk + PK_W0;  }
    else if (t < 4096)  { W = W1; K = 128; NC = 128; local = t - 2048;   dst = pk + PK_W1;  }
    else if (t < 6144)  { W = W2; K = 128; NC = 128; local = t - 4096;   dst = pk + PK_W2;  }
    else if (t < 8192)  { W = Wg; K = 128; NC = 128; local = t - 6144;   dst = pk + PK_WG;  }
    else if (t < 10240) { W = R0; K = 128; NC = 128; local = t - 8192;   dst = pk + PK_R0A; }
    else if (t < 12288) { W = R0; K = 128; NC = 128; local = t - 10240;  dst = pk + PK_R0B; rb = 128; }
    else if (t < 13312) { W = R1; K = 128; NC = 64;  local = t - 12288;  dst = pk + PK_R1;  }
    else return;
    int lane = local & 63;
    int frag = local >> 6;
    int nks  = K >> 5;
    int ks   = frag % nks;
    int ct   = frag / nks;
    int row0 = rb + ks * 32 + ((lane >> 4) << 3);
    int col  = ct * 16 + (lane & 15);
    f16x8 v;
    #pragma unroll
    for (int i = 0; i < 8; ++i) v[i] = (f16)W[(size_t)(row0 + i) * NC + col];
    *(f16x8*)(dst + (size_t)local * 8) = v;
}

// ----------------------- counting sort by src (full) ------------------------
__global__ void zero_kernel(u32* __restrict__ p, int n)
{
    int i = blockIdx.x * blockDim.x + threadIdx.x;
    for (; i < n; i += gridDim.x * blockDim.x) p[i] = 0;
}

__global__ void hist_full(const int* __restrict__ src, u32* __restrict__ cnt, int E)
{
    int i = blockIdx.x * blockDim.x + threadIdx.x;
    int stride = gridDim.x * blockDim.x;
    for (; i < E; i += stride) atomicAdd(&cnt[src[i]], 1u);
}

// single-block exclusive scan over nb <= 65536 bins (1024 thr x 64 seq each)
__global__ __launch_bounds__(1024)
void scan_full(u32* __restrict__ cnt, int nb)
{
    __shared__ u32 part[1024];
    const int t = threadIdx.x;
    u32 loc[64];
    u32 s = 0;
    #pragma unroll
    for (int i = 0; i < 64; ++i) {
        int idx = t * 64 + i;
        u32 c = (idx < nb) ? cnt[idx] : 0u;
        loc[i] = c; s += c;
    }
    part[t] = s;
    __syncthreads();
    for (int off = 1; off < 1024; off <<= 1) {
        u32 x = (t >= off) ? part[t - off] : 0u;
        __syncthreads();
        part[t] += x;
        __syncthreads();
    }
    u32 run = (t == 0) ? 0u : part[t - 1];
    #pragma unroll
    for (int i = 0; i < 64; ++i) {
        int idx = t * 64 + i;
        if (idx < nb) { u32 c = loc[i]; cnt[idx] = run; run += c; }
    }
}

__global__ void scatter_full(const int* __restrict__ src, const int* __restrict__ dst,
                             u32* __restrict__ base,
                             int* __restrict__ src_s, int* __restrict__ dst_s,
                             int* __restrict__ eid_s, int E)
{
    int i = blockIdx.x * blockDim.x + threadIdx.x;
    int stride = gridDim.x * blockDim.x;
    for (; i < E; i += stride) {
        int s = src[i];
        u32 pos = atomicAdd(&base[s], 1u);
        src_s[pos] = s; dst_s[pos] = dst[i]; eid_s[pos] = i;
    }
}

// ---------------- Node phase (round-5 verified TWO-BUFFER version, ~30 us):
// x = sigmoid(z@Wg+bg)*z; u = x@R0a + r0; v = x@R0b. 128 nodes/block, 4 waves;
// wave owns rows [32w,32w+32) as two 16-row tiles sharing every B-frag load.
// DO NOT convert to single-buffer in-place: measured +20 us twice (r7, r9).
__global__ __launch_bounds__(256, 2)
void node_mlp_mfma(const float* __restrict__ h, const f16* __restrict__ pk,
                   const float* __restrict__ b0, const float* __restrict__ b1,
                   const float* __restrict__ b2, const float* __restrict__ bg,
                   const float* __restrict__ r0,
                   f16* __restrict__ ug, f16* __restrict__ vg, int N)
{
    __shared__ f16 zA[128 * 136];
    __shared__ f16 zB[128 * 136];
    const int t = threadIdx.x;
    const int lane = t & 63;
    const int w = t >> 6;
    const int n0 = blockIdx.x * 128;

    {
        int c4 = t & 31, rr = t >> 5;
        #pragma unroll
        for (int i = 0; i < 16; ++i) {
            int r = rr + 8 * i;
            int node = n0 + r; if (node >= N) node = N - 1;
            float4 v = *(const float4*)(h + (size_t)node * DH + c4 * 4);
            f16x4 o; o[0] = (f16)v.x; o[1] = (f16)v.y; o[2] = (f16)v.z; o[3] = (f16)v.w;
            *(f16x4*)(&zA[r * 136 + c4 * 4]) = o;
        }
    }
    __syncthreads();

    const int lr = lane & 15;
    const int lg = lane >> 4;
    const int rowA = w * 32 + lr;

    auto do_layer = [&](const f16* zin, const f16* pw, const float* bias,
                        bool do_relu, f16* zout) {
        f16x8 A0[4], A1[4];
        #pragma unroll
        for (int ks = 0; ks < 4; ++ks) {
            A0[ks] = *(const f16x8*)(&zin[rowA * 136 + ks * 32 + lg * 8]);
            A1[ks] = *(const f16x8*)(&zin[(rowA + 16) * 136 + ks * 32 + lg * 8]);
        }
        #pragma unroll
        for (int ct = 0; ct < 8; ++ct) {
            f32x4 acc0 = {0.f, 0.f, 0.f, 0.f};
            f32x4 acc1 = {0.f, 0.f, 0.f, 0.f};
            #pragma unroll
            for (int ks = 0; ks < 4; ++ks) {
                f16x8 B = *(const f16x8*)(pw + ((ct * 4 + ks) * 64 + lane) * 8);
                acc0 = __builtin_amdgcn_mfma_f32_16x16x32_f16(A0[ks], B, acc0, 0, 0, 0);
                acc1 = __builtin_amdgcn_mfma_f32_16x16x32_f16(A1[ks], B, acc1, 0, 0, 0);
            }
            float bj = bias ? bias[ct * 16 + lr] : 0.f;
            #pragma unroll
            for (int r = 0; r < 4; ++r) {
                float v0 = acc0[r] + bj;
                float v1 = acc1[r] + bj;
                if (do_relu) { v0 = fmaxf(v0, 0.f); v1 = fmaxf(v1, 0.f); }
                zout[(w * 32 + lg * 4 + r) * 136 + ct * 16 + lr] = (f16)v0;
                zout[(w * 32 + 16 + lg * 4 + r) * 136 + ct * 16 + lr] = (f16)v1;
            }
        }
    };
    auto copy_out = [&](const f16* zsrc, f16* gdst) {
        int c8 = t & 15, rr = t >> 4;
        #pragma unroll
        for (int i = 0; i < 8; ++i) {
            int r = rr + 16 * i;
            int node = n0 + r;
            if (node < N) {
                uint4 vv = *(const uint4*)(&zsrc[r * 136 + c8 * 8]);
                *(uint4*)(gdst + (size_t)node * DH + c8 * 8) = vv;
            }
        }
    };

    do_layer(zA, pk + PK_W0, b0, true, zB);
    do_layer(zB, pk + PK_W1, b1, true, zA);
    do_layer(zA, pk + PK_W2, b2, true, zB);

    // gate: x = sigmoid(zB@Wg + bg) * zB -> zA
    {
        f16x8 A0[4], A1[4];
        #pragma unroll
        for (int ks = 0; ks < 4; ++ks) {
            A0[ks] = *(const f16x8*)(&zB[rowA * 136 + ks * 32 + lg * 8]);
            A1[ks] = *(const f16x8*)(&zB[(rowA + 16) * 136 + ks * 32 + lg * 8]);
        }
        #pragma unroll
        for (int ct = 0; ct < 8; ++ct) {
            f32x4 acc0 = {0.f, 0.f, 0.f, 0.f};
            f32x4 acc1 = {0.f, 0.f, 0.f, 0.f};
            #pragma unroll
            for (int ks = 0; ks < 4; ++ks) {
                f16x8 B = *(const f16x8*)(pk + PK_WG + ((ct * 4 + ks) * 64 + lane) * 8);
                acc0 = __builtin_amdgcn_mfma_f32_16x16x32_f16(A0[ks], B, acc0, 0, 0, 0);
                acc1 = __builtin_amdgcn_mfma_f32_16x16x32_f16(A1[ks], B, acc1, 0, 0, 0);
            }
            float bj = bg[ct * 16 + lr];
            #pragma unroll
            for (int r = 0; r < 4; ++r) {
                int row0 = w * 32 + lg * 4 + r;
                int row1 = row0 + 16;
                float g0 = acc0[r] + bj, g1 = acc1[r] + bj;
                g0 = 1.f / (1.f + __expf(-g0));
                g1 = 1.f / (1.f + __expf(-g1));
                float z0 = (float)zB[row0 * 136 + ct * 16 + lr];
                float z1 = (float)zB[row1 * 136 + ct * 16 + lr];
                zA[row0 * 136 + ct * 16 + lr] = (f16)(g0 * z0);
                zA[row1 * 136 + ct * 16 + lr] = (f16)(g1 * z1);
            }
        }
    }
    do_layer(zA, pk + PK_R0A, r0, false, zB);
    __syncthreads();
    copy_out(zB, ug);
    __syncthreads();
    do_layer(zA, pk + PK_R0B, nullptr, false, zB);
    __syncthreads();
    copy_out(zB, vg);
}

// ---------------- Edge phase: out[eid] = (relu(relu(u[s]+v[d]) @ R1 + r1)) @ R2 + r2
// Verified 66 us structure; s/d arrays may be src-sorted (runs of ~16 equal src
// make the u-gather same-line -> wave coalescer merges -> fewer L1 misses).
// eidp scatters outputs back to original edge ids (nullptr -> identity).
// NOTE: launch_bounds must stay (256,2) — (256,5) spills Bw[16] (round 6).
__global__ __launch_bounds__(256, 2)
void edge_mlp_v5(const f16* __restrict__ u, const f16* __restrict__ v,
                 const int* __restrict__ s_arr, const int* __restrict__ d_arr,
                 const int* __restrict__ eidp,
                 const f16* __restrict__ pk,
                 const float* __restrict__ r1, const float* __restrict__ R2,
                 const float* __restrict__ r2,
                 float* __restrict__ out, int E, int ngroups, int nwaves)
{
    const int t = threadIdx.x;
    const int lane = t & 63;
    const int lr = lane & 15, lg = lane >> 4;
    const int wid = (int)((blockIdx.x * blockDim.x + t) >> 6);

    f16x8 Bw[16];
    #pragma unroll
    for (int f = 0; f < 16; ++f)
        Bw[f] = *(const f16x8*)(pk + PK_R1 + ((size_t)(f * 64 + lane)) * 8);

    f32x4 r1f[4];
    #pragma unroll
    for (int ct = 0; ct < 4; ++ct)
        r1f[ct] = *(const f32x4*)(r1 + ct * 16 + lg * 4);

    float R2f0[16], R2f1[16];
    #pragma unroll
    for (int ct = 0; ct < 4; ++ct)
        #pragma unroll
        for (int r = 0; r < 4; ++r) {
            int k = ct * 16 + lg * 4 + r;
            R2f0[ct * 4 + r] = R2[k * 2 + 0];
            R2f1[ct * 4 + r] = R2[k * 2 + 1];
        }
    const float ob0 = r2[0], ob1 = r2[1];

    int g = wid;
    if (g >= ngroups) return;

    int e0 = g * 16 + lr; if (e0 >= E) e0 = E - 1;
    int sc = s_arr[e0], dc = d_arr[e0];
    f16x8 Uc[4], Vc[4];
    {
        const f16* ur = u + (size_t)sc * DH + lg * 8;
        const f16* vr = v + (size_t)dc * DH + lg * 8;
        #pragma unroll
        for (int ks = 0; ks < 4; ++ks) {
            Uc[ks] = *(const f16x8*)(ur + ks * 32);
            Vc[ks] = *(const f16x8*)(vr + ks * 32);
        }
    }
    int sn = 0, dn = 0;
    if (g + nwaves < ngroups) {
        int en = (g + nwaves) * 16 + lr; if (en >= E) en = E - 1;
        sn = s_arr[en]; dn = d_arr[en];
    }

    while (g < ngroups) {
        const int gnext = g + nwaves;
        int eo = g * 16 + lr;
        int ecl = eo < E ? eo : E - 1;
        int ecur = eidp ? eidp[ecl] : ecl;

        f16x8 Un[4], Vn[4];
        if (gnext < ngroups) {
            const f16* ur = u + (size_t)sn * DH + lg * 8;
            const f16* vr = v + (size_t)dn * DH + lg * 8;
            #pragma unroll
            for (int ks = 0; ks < 4; ++ks) {
                Un[ks] = *(const f16x8*)(ur + ks * 32);
                Vn[ks] = *(const f16x8*)(vr + ks * 32);
            }
        }
        int g2 = g + 2 * nwaves;
        int s2 = 0, d2 = 0;
        if (g2 < ngroups) {
            int e2 = g2 * 16 + lr; if (e2 >= E) e2 = E - 1;
            s2 = s_arr[e2]; d2 = d_arr[e2];
        }

        // y1 fragments: relu(u + v)  (r0 folded into u)
        f16x8 A[4];
        #pragma unroll
        for (int ks = 0; ks < 4; ++ks) {
            f16x8 s = Uc[ks] + Vc[ks];
            #pragma unroll
            for (int i = 0; i < 8; ++i) s[i] = s[i] > (f16)0 ? s[i] : (f16)0;
            A[ks] = s;
        }

        // L2 GEMM (swapped): D[outcol][edge], lane holds edge (lane&15)
        f32x4 a0 = {0.f,0.f,0.f,0.f}, a1 = {0.f,0.f,0.f,0.f};
        f32x4 a2 = {0.f,0.f,0.f,0.f}, a3 = {0.f,0.f,0.f,0.f};
        #pragma unroll
        for (int ks = 0; ks < 4; ++ks) {
            a0 = __builtin_amdgcn_mfma_f32_16x16x32_f16(Bw[0*4+ks], A[ks], a0, 0, 0, 0);
            a1 = __builtin_amdgcn_mfma_f32_16x16x32_f16(Bw[1*4+ks], A[ks], a1, 0, 0, 0);
            a2 = __builtin_amdgcn_mfma_f32_16x16x32_f16(Bw[2*4+ks], A[ks], a2, 0, 0, 0);
            a3 = __builtin_amdgcn_mfma_f32_16x16x32_f16(Bw[3*4+ks], A[ks], a3, 0, 0, 0);
        }

        // bias + relu + L3 partial dot; r2 bias added once by writing lane
        float p0 = 0.f, p1 = 0.f;
        #pragma unroll
        for (int r = 0; r < 4; ++r) {
            float y;
            y = fmaxf(a0[r] + r1f[0][r], 0.f); p0 = fmaf(y, R2f0[0*4+r], p0); p1 = fmaf(y, R2f1[0*4+r], p1);
            y = fmaxf(a1[r] + r1f[1][r], 0.f); p0 = fmaf(y, R2f0[1*4+r], p0); p1 = fmaf(y, R2f1[1*4+r], p1);
            y = fmaxf(a2[r] + r1f[2][r], 0.f); p0 = fmaf(y, R2f0[2*4+r], p0); p1 = fmaf(y, R2f1[2*4+r], p1);
            y = fmaxf(a3[r] + r1f[3][r], 0.f); p0 = fmaf(y, R2f0[3*4+r], p0); p1 = fmaf(y, R2f1[3*4+r], p1);
        }
        float q;
        q = __shfl_xor(p0, 16); p0 += q;
        q = __shfl_xor(p0, 32); p0 += q;
        q = __shfl_xor(p1, 16); p1 += q;
        q = __shfl_xor(p1, 32); p1 += q;
        if (lg == 0 && eo < E)
            *(float2*)(out + (size_t)ecur * 2) = make_float2(p0 + ob0, p1 + ob1);

        #pragma unroll
        for (int ks = 0; ks < 4; ++ks) { Uc[ks] = Un[ks]; Vc[ks] = Vn[ks]; }
        sc = sn; dc = dn; sn = s2; dn = d2;
        g = gnext;
    }
}

extern "C" void kernel_launch(void* const* d_in, const int* in_sizes, int n_in,
                              void* d_out, int out_size, void* d_ws, size_t ws_size,
                              hipStream_t stream)
{
    const float* h   = (const float*)d_in[0];
    const int*   src = (const int*)d_in[1];
    const int*   dst = (const int*)d_in[2];
    const float* W0  = (const float*)d_in[3];
    const float* b0  = (const float*)d_in[4];
    const float* W1  = (const float*)d_in[5];
    const float* b1  = (const float*)d_in[6];
    const float* W2  = (const float*)d_in[7];
    const float* b2  = (const float*)d_in[8];
    const float* Wg  = (const float*)d_in[9];
    const float* bg  = (const float*)d_in[10];
    const float* R0  = (const float*)d_in[11];
    const float* r0  = (const float*)d_in[12];
    const float* R1  = (const float*)d_in[13];
    const float* r1  = (const float*)d_in[14];
    const float* R2  = (const float*)d_in[15];
    const float* r2  = (const float*)d_in[16];

    const int N = in_sizes[0] / DH;
    const int E = in_sizes[1];

    char* wsb = (char*)d_ws;
    size_t off = 0;
    f16* pk = (f16*)(wsb + off);       off += 262144;
    f16* ug = (f16*)(wsb + off);       off += (size_t)N * DH * 2;
    f16* vg = (f16*)(wsb + off);       off += (size_t)N * DH * 2;
    u32* cnt   = (u32*)(wsb + off);    off += (size_t)((N + 1023) & ~1023) * 4;
    int* src_s = (int*)(wsb + off);    off += (size_t)E * 4;
    int* dst_s = (int*)(wsb + off);    off += (size_t)E * 4;
    int* eid_s = (int*)(wsb + off);    off += (size_t)E * 4;
    const bool use_sort = (off <= ws_size) && (N <= 65536);

    pack_weights_kernel<<<dim3(52), dim3(256), 0, stream>>>(W0, W1, W2, Wg, R0, R1, pk);
    node_mlp_mfma<<<dim3((N + 127) / 128), dim3(256), 0, stream>>>(
        h, pk, b0, b1, b2, bg, r0, ug, vg, N);

    const int ngroups = (E + 15) / 16;
    const int nblocks = 1024;
    const int nwaves  = nblocks * 4;

    if (use_sort) {
        zero_kernel<<<dim3(64), dim3(256), 0, stream>>>(cnt, N);
        hist_full<<<dim3(512), dim3(256), 0, stream>>>(src, cnt, E);
        scan_full<<<dim3(1), dim3(1024), 0, stream>>>(cnt, N);
        scatter_full<<<dim3(512), dim3(256), 0, stream>>>(src, dst, cnt,
                                                          src_s, dst_s, eid_s, E);
        edge_mlp_v5<<<dim3(nblocks), dim3(256), 0, stream>>>(
            ug, vg, src_s, dst_s, eid_s, pk, r1, R2, r2, (float*)d_out, E, ngroups, nwaves);
    } else {
        edge_mlp_v5<<<dim3(nblocks), dim3(256), 0, stream>>>(
            ug, vg, src, dst, nullptr, pk, r1, R2, r2, (float*)d_out, E, ngroups, nwaves);
    }
}

// Round 11
// 100.210 us; speedup vs baseline: 2.2577x; 2.2577x over previous
//
#include <hip/hip_runtime.h>
#include <hip/hip_bf16.h>
#include <cstdint>

typedef _Float16 f16;
typedef _Float16 f16x8 __attribute__((ext_vector_type(8)));
typedef _Float16 f16x4 __attribute__((ext_vector_type(4)));
typedef float    f32x4 __attribute__((ext_vector_type(4)));

#define DH 128

// Packed f16 weight layout (fragments for v_mfma_f32_16x16x32_f16):
//   packed[((ct*NKS + ks)*64 + lane)*8 + i] = W[rb + ks*32 + (lane>>4)*8 + i][ct*16 + (lane&15)]
#define PK_W0   0
#define PK_W1   16384
#define PK_W2   32768
#define PK_WG   49152
#define PK_R0A  65536
#define PK_R0B  81920
#define PK_R1   98304
#define PK_TOTAL 106496

// ---------------------------------------------------------------------------
// Session ledger (dur_us total: 1318 -> 196 -> 116 -> 104 -> ... -> ~100):
//  * edge kernel walled at ~66 us by gather-miss throughput (~4 x 128B
//    lines/edge, ~11.8 cyc/line/CU): grid-size null (r5), L2-bucket-pinning
//    cut fetch 35% / time null (r8), full src-sort cut fetch 46% / time -16%
//    but any permutation materialization costs ~3-9x its gain (r6/r8/r10).
//  * node kernel must stay TWO-BUFFER (in-place LDS variant +20 us, r7/r9).
//  * edge launch_bounds must stay (256,2): (256,5) spills Bw[16] (r6, 4x).
// ---------------------------------------------------------------------------

__global__ void pack_weights_kernel(const float* __restrict__ W0, const float* __restrict__ W1,
                                    const float* __restrict__ W2, const float* __restrict__ Wg,
                                    const float* __restrict__ R0, const float* __restrict__ R1,
                                    f16* __restrict__ pk)
{
    int t = blockIdx.x * 256 + threadIdx.x;
    const float* W; int K, NC, local, rb = 0; f16* dst;
    if      (t < 2048)  { W = W0; K = 128; NC = 128; local = t;          dst = pk + PK_W0;  }
    else if (t < 4096)  { W = W1; K = 128; NC = 128; local = t - 2048;   dst = pk + PK_W1;  }
    else if (t < 6144)  { W = W2; K = 128; NC = 128; local = t - 4096;   dst = pk + PK_W2;  }
    else if (t < 8192)  { W = Wg; K = 128; NC = 128; local = t - 6144;   dst = pk + PK_WG;  }
    else if (t < 10240) { W = R0; K = 128; NC = 128; local = t - 8192;   dst = pk + PK_R0A; }
    else if (t < 12288) { W = R0; K = 128; NC = 128; local = t - 10240;  dst = pk + PK_R0B; rb = 128; }
    else if (t < 13312) { W = R1; K = 128; NC = 64;  local = t - 12288;  dst = pk + PK_R1;  }
    else return;
    int lane = local & 63;
    int frag = local >> 6;
    int nks  = K >> 5;
    int ks   = frag % nks;
    int ct   = frag / nks;
    int row0 = rb + ks * 32 + ((lane >> 4) << 3);
    int col  = ct * 16 + (lane & 15);
    f16x8 v;
    #pragma unroll
    for (int i = 0; i < 8; ++i) v[i] = (f16)W[(size_t)(row0 + i) * NC + col];
    *(f16x8*)(dst + (size_t)local * 8) = v;
}

// ---------------- Node phase: x = sigmoid(z@Wg+bg)*z; u = x@R0a + r0; v = x@R0b
// 128 nodes/block, 4 waves; wave owns rows [32w,32w+32) as two 16-row tiles
// sharing every B-fragment load (2 MFMAs per B read).
__global__ __launch_bounds__(256, 2)
void node_mlp_mfma(const float* __restrict__ h, const f16* __restrict__ pk,
                   const float* __restrict__ b0, const float* __restrict__ b1,
                   const float* __restrict__ b2, const float* __restrict__ bg,
                   const float* __restrict__ r0,
                   f16* __restrict__ ug, f16* __restrict__ vg, int N)
{
    __shared__ f16 zA[128 * 136];
    __shared__ f16 zB[128 * 136];
    const int t = threadIdx.x;
    const int lane = t & 63;
    const int w = t >> 6;
    const int n0 = blockIdx.x * 128;

    {
        int c4 = t & 31, rr = t >> 5;
        #pragma unroll
        for (int i = 0; i < 16; ++i) {
            int r = rr + 8 * i;
            int node = n0 + r; if (node >= N) node = N - 1;
            float4 v = *(const float4*)(h + (size_t)node * DH + c4 * 4);
            f16x4 o; o[0] = (f16)v.x; o[1] = (f16)v.y; o[2] = (f16)v.z; o[3] = (f16)v.w;
            *(f16x4*)(&zA[r * 136 + c4 * 4]) = o;
        }
    }
    __syncthreads();

    const int lr = lane & 15;
    const int lg = lane >> 4;
    const int rowA = w * 32 + lr;

    auto do_layer = [&](const f16* zin, const f16* pw, const float* bias,
                        bool do_relu, f16* zout) {
        f16x8 A0[4], A1[4];
        #pragma unroll
        for (int ks = 0; ks < 4; ++ks) {
            A0[ks] = *(const f16x8*)(&zin[rowA * 136 + ks * 32 + lg * 8]);
            A1[ks] = *(const f16x8*)(&zin[(rowA + 16) * 136 + ks * 32 + lg * 8]);
        }
        #pragma unroll
        for (int ct = 0; ct < 8; ++ct) {
            f32x4 acc0 = {0.f, 0.f, 0.f, 0.f};
            f32x4 acc1 = {0.f, 0.f, 0.f, 0.f};
            #pragma unroll
            for (int ks = 0; ks < 4; ++ks) {
                f16x8 B = *(const f16x8*)(pw + ((ct * 4 + ks) * 64 + lane) * 8);
                acc0 = __builtin_amdgcn_mfma_f32_16x16x32_f16(A0[ks], B, acc0, 0, 0, 0);
                acc1 = __builtin_amdgcn_mfma_f32_16x16x32_f16(A1[ks], B, acc1, 0, 0, 0);
            }
            float bj = bias ? bias[ct * 16 + lr] : 0.f;
            #pragma unroll
            for (int r = 0; r < 4; ++r) {
                float v0 = acc0[r] + bj;
                float v1 = acc1[r] + bj;
                if (do_relu) { v0 = fmaxf(v0, 0.f); v1 = fmaxf(v1, 0.f); }
                zout[(w * 32 + lg * 4 + r) * 136 + ct * 16 + lr] = (f16)v0;
                zout[(w * 32 + 16 + lg * 4 + r) * 136 + ct * 16 + lr] = (f16)v1;
            }
        }
    };
    auto copy_out = [&](const f16* zsrc, f16* gdst) {
        int c8 = t & 15, rr = t >> 4;
        #pragma unroll
        for (int i = 0; i < 8; ++i) {
            int r = rr + 16 * i;
            int node = n0 + r;
            if (node < N) {
                uint4 vv = *(const uint4*)(&zsrc[r * 136 + c8 * 8]);
                *(uint4*)(gdst + (size_t)node * DH + c8 * 8) = vv;
            }
        }
    };

    do_layer(zA, pk + PK_W0, b0, true, zB);
    do_layer(zB, pk + PK_W1, b1, true, zA);
    do_layer(zA, pk + PK_W2, b2, true, zB);

    // gate: x = sigmoid(zB@Wg + bg) * zB -> zA
    {
        f16x8 A0[4], A1[4];
        #pragma unroll
        for (int ks = 0; ks < 4; ++ks) {
            A0[ks] = *(const f16x8*)(&zB[rowA * 136 + ks * 32 + lg * 8]);
            A1[ks] = *(const f16x8*)(&zB[(rowA + 16) * 136 + ks * 32 + lg * 8]);
        }
        #pragma unroll
        for (int ct = 0; ct < 8; ++ct) {
            f32x4 acc0 = {0.f, 0.f, 0.f, 0.f};
            f32x4 acc1 = {0.f, 0.f, 0.f, 0.f};
            #pragma unroll
            for (int ks = 0; ks < 4; ++ks) {
                f16x8 B = *(const f16x8*)(pk + PK_WG + ((ct * 4 + ks) * 64 + lane) * 8);
                acc0 = __builtin_amdgcn_mfma_f32_16x16x32_f16(A0[ks], B, acc0, 0, 0, 0);
                acc1 = __builtin_amdgcn_mfma_f32_16x16x32_f16(A1[ks], B, acc1, 0, 0, 0);
            }
            float bj = bg[ct * 16 + lr];
            #pragma unroll
            for (int r = 0; r < 4; ++r) {
                int row0 = w * 32 + lg * 4 + r;
                int row1 = row0 + 16;
                float g0 = acc0[r] + bj, g1 = acc1[r] + bj;
                g0 = 1.f / (1.f + __expf(-g0));
                g1 = 1.f / (1.f + __expf(-g1));
                float z0 = (float)zB[row0 * 136 + ct * 16 + lr];
                float z1 = (float)zB[row1 * 136 + ct * 16 + lr];
                zA[row0 * 136 + ct * 16 + lr] = (f16)(g0 * z0);
                zA[row1 * 136 + ct * 16 + lr] = (f16)(g1 * z1);
            }
        }
    }
    do_layer(zA, pk + PK_R0A, r0, false, zB);
    __syncthreads();
    copy_out(zB, ug);
    __syncthreads();
    do_layer(zA, pk + PK_R0B, nullptr, false, zB);
    __syncthreads();
    copy_out(zB, vg);
}

// ---------------- Edge phase: out = (relu(relu(u[src]+v[dst]) @ R1 + r1)) @ R2 + r2
// Zero LDS. 16 edges per wave-iteration, grid-stride. R1 fragments persist in
// VGPRs; gathers land directly in MFMA fragment registers.
__global__ __launch_bounds__(256, 2)
void edge_mlp_v3(const f16* __restrict__ u, const f16* __restrict__ v,
                 const int* __restrict__ src, const int* __restrict__ dst,
                 const f16* __restrict__ pk,
                 const float* __restrict__ r1, const float* __restrict__ R2,
                 const float* __restrict__ r2,
                 float* __restrict__ out, int E, int ngroups, int nwaves)
{
    const int t = threadIdx.x;
    const int lane = t & 63;
    const int lr = lane & 15, lg = lane >> 4;
    const int wid = (int)((blockIdx.x * blockDim.x + t) >> 6);

    f16x8 Bw[16];
    #pragma unroll
    for (int f = 0; f < 16; ++f)
        Bw[f] = *(const f16x8*)(pk + PK_R1 + ((size_t)(f * 64 + lane)) * 8);

    f32x4 r1f[4];
    #pragma unroll
    for (int ct = 0; ct < 4; ++ct)
        r1f[ct] = *(const f32x4*)(r1 + ct * 16 + lg * 4);

    float R2f0[16], R2f1[16];
    #pragma unroll
    for (int ct = 0; ct < 4; ++ct)
        #pragma unroll
        for (int r = 0; r < 4; ++r) {
            int k = ct * 16 + lg * 4 + r;
            R2f0[ct * 4 + r] = R2[k * 2 + 0];
            R2f1[ct * 4 + r] = R2[k * 2 + 1];
        }
    const float ob0 = r2[0], ob1 = r2[1];

    int g = wid;
    if (g >= ngroups) return;

    int e0 = g * 16 + lr; if (e0 >= E) e0 = E - 1;
    int sc = src[e0], dc = dst[e0];
    f16x8 Uc[4], Vc[4];
    {
        const f16* ur = u + (size_t)sc * DH + lg * 8;
        const f16* vr = v + (size_t)dc * DH + lg * 8;
        #pragma unroll
        for (int ks = 0; ks < 4; ++ks) {
            Uc[ks] = *(const f16x8*)(ur + ks * 32);
            Vc[ks] = *(const f16x8*)(vr + ks * 32);
        }
    }
    int sn = 0, dn = 0;
    if (g + nwaves < ngroups) {
        int en = (g + nwaves) * 16 + lr; if (en >= E) en = E - 1;
        sn = src[en]; dn = dst[en];
    }

    while (g < ngroups) {
        const int gnext = g + nwaves;
        f16x8 Un[4], Vn[4];
        if (gnext < ngroups) {
            const f16* ur = u + (size_t)sn * DH + lg * 8;
            const f16* vr = v + (size_t)dn * DH + lg * 8;
            #pragma unroll
            for (int ks = 0; ks < 4; ++ks) {
                Un[ks] = *(const f16x8*)(ur + ks * 32);
                Vn[ks] = *(const f16x8*)(vr + ks * 32);
            }
        }
        int g2 = g + 2 * nwaves;
        int s2 = 0, d2 = 0;
        if (g2 < ngroups) {
            int e2 = g2 * 16 + lr; if (e2 >= E) e2 = E - 1;
            s2 = src[e2]; d2 = dst[e2];
        }

        // y1 fragments: relu(u + v)  (r0 folded into u)
        f16x8 A[4];
        #pragma unroll
        for (int ks = 0; ks < 4; ++ks) {
            f16x8 s = Uc[ks] + Vc[ks];
            #pragma unroll
            for (int i = 0; i < 8; ++i) s[i] = s[i] > (f16)0 ? s[i] : (f16)0;
            A[ks] = s;
        }

        // L2 GEMM (swapped): D[outcol][edge], lane holds edge (lane&15)
        f32x4 a0 = {0.f,0.f,0.f,0.f}, a1 = {0.f,0.f,0.f,0.f};
        f32x4 a2 = {0.f,0.f,0.f,0.f}, a3 = {0.f,0.f,0.f,0.f};
        #pragma unroll
        for (int ks = 0; ks < 4; ++ks) {
            a0 = __builtin_amdgcn_mfma_f32_16x16x32_f16(Bw[0*4+ks], A[ks], a0, 0, 0, 0);
            a1 = __builtin_amdgcn_mfma_f32_16x16x32_f16(Bw[1*4+ks], A[ks], a1, 0, 0, 0);
            a2 = __builtin_amdgcn_mfma_f32_16x16x32_f16(Bw[2*4+ks], A[ks], a2, 0, 0, 0);
            a3 = __builtin_amdgcn_mfma_f32_16x16x32_f16(Bw[3*4+ks], A[ks], a3, 0, 0, 0);
        }

        // bias + relu + L3 partial dot; r2 bias added once by writing lane
        float p0 = 0.f, p1 = 0.f;
        #pragma unroll
        for (int r = 0; r < 4; ++r) {
            float y;
            y = fmaxf(a0[r] + r1f[0][r], 0.f); p0 = fmaf(y, R2f0[0*4+r], p0); p1 = fmaf(y, R2f1[0*4+r], p1);
            y = fmaxf(a1[r] + r1f[1][r], 0.f); p0 = fmaf(y, R2f0[1*4+r], p0); p1 = fmaf(y, R2f1[1*4+r], p1);
            y = fmaxf(a2[r] + r1f[2][r], 0.f); p0 = fmaf(y, R2f0[2*4+r], p0); p1 = fmaf(y, R2f1[2*4+r], p1);
            y = fmaxf(a3[r] + r1f[3][r], 0.f); p0 = fmaf(y, R2f0[3*4+r], p0); p1 = fmaf(y, R2f1[3*4+r], p1);
        }
        float q;
        q = __shfl_xor(p0, 16); p0 += q;
        q = __shfl_xor(p0, 32); p0 += q;
        q = __shfl_xor(p1, 16); p1 += q;
        q = __shfl_xor(p1, 32); p1 += q;
        int eo = g * 16 + lr;
        if (lg == 0 && eo < E)
            *(float2*)(out + (size_t)eo * 2) = make_float2(p0 + ob0, p1 + ob1);

        #pragma unroll
        for (int ks = 0; ks < 4; ++ks) { Uc[ks] = Un[ks]; Vc[ks] = Vn[ks]; }
        sc = sn; dc = dn; sn = s2; dn = d2;
        g = gnext;
    }
}

extern "C" void kernel_launch(void* const* d_in, const int* in_sizes, int n_in,
                              void* d_out, int out_size, void* d_ws, size_t ws_size,
                              hipStream_t stream)
{
    const float* h   = (const float*)d_in[0];
    const int*   src = (const int*)d_in[1];
    const int*   dst = (const int*)d_in[2];
    const float* W0  = (const float*)d_in[3];
    const float* b0  = (const float*)d_in[4];
    const float* W1  = (const float*)d_in[5];
    const float* b1  = (const float*)d_in[6];
    const float* W2  = (const float*)d_in[7];
    const float* b2  = (const float*)d_in[8];
    const float* Wg  = (const float*)d_in[9];
    const float* bg  = (const float*)d_in[10];
    const float* R0  = (const float*)d_in[11];
    const float* r0  = (const float*)d_in[12];
    const float* R1  = (const float*)d_in[13];
    const float* r1  = (const float*)d_in[14];
    const float* R2  = (const float*)d_in[15];
    const float* r2  = (const float*)d_in[16];

    const int N = in_sizes[0] / DH;
    const int E = in_sizes[1];

    f16* pk = (f16*)d_ws;                        // 208 KB packed weights
    f16* ug = pk + PK_TOTAL;                     // N*128 f16
    f16* vg = ug + (size_t)N * DH;               // N*128 f16

    pack_weights_kernel<<<dim3(52), dim3(256), 0, stream>>>(W0, W1, W2, Wg, R0, R1, pk);
    node_mlp_mfma<<<dim3((N + 127) / 128), dim3(256), 0, stream>>>(
        h, pk, b0, b1, b2, bg, r0, ug, vg, N);

    const int ngroups = (E + 15) / 16;
    const int nblocks = 1024;
    const int nwaves  = nblocks * 4;
    edge_mlp_v3<<<dim3(nblocks), dim3(256), 0, stream>>>(
        ug, vg, src, dst, pk, r1, R2, r2, (float*)d_out, E, ngroups, nwaves);
}